// Round 13
// baseline (258.653 us; speedup 1.0000x reference)
//
#include <hip/hip_runtime.h>
#include <hip/hip_bf16.h>
#include <math.h>

#define NB 65536
#define DIN 1024
#define NQ 64
#define DOUT 1024

typedef __attribute__((ext_vector_type(8))) short bf16x8;
typedef __attribute__((ext_vector_type(4))) float f32x4;
typedef unsigned short u16;

__device__ __forceinline__ u16 f2bf(float f) {
    union { float f; unsigned u; } v; v.f = f;
    return (u16)((v.u + 0x7fffu + ((v.u >> 16) & 1u)) >> 16);
}

// ---- kP: row-major bf16 weights + per-q constants (round-1 verbatim) --------
__global__ __launch_bounds__(256) void kP(const float* __restrict__ W_in,
                                          const float* __restrict__ W_out,
                                          const float* __restrict__ qp,
                                          u16* __restrict__ Wb,
                                          u16* __restrict__ Wob,
                                          float* __restrict__ cp0,
                                          float* __restrict__ cq) {
    int i = blockIdx.x * 256 + threadIdx.x;
    if (i < NQ * DIN)  Wb[i]  = f2bf(W_in[i]);
    if (i < DOUT * NQ) Wob[i] = f2bf(W_out[i]);
    if (i < NQ) {
        cp0[i] = cosf(qp[i * 3 + 0]);
        cq[i]  = sinf(qp[i * 3 + 1]) * cosf(qp[i * 3 + 2]);
    }
}

// ---- kA: GEMM1 + quantum epilogue -> row-major state ------------------------
// 4096 blocks x 256 thr. Block owns 16 rows; wave w owns q-tile w (full K).
// Round-1 kA with wave->q-tile split (B-frag address formula verbatim:
// (n*16+r)*DIN + k0 + kg*8 with n=w). No LDS, no barriers, no precomputed
// permutations. Hw transcendentals validated rounds 2-10.
__global__ __launch_bounds__(256) void kA(const float* __restrict__ x,
                                          const u16* __restrict__ Wb,
                                          const float* __restrict__ b_in,
                                          const float* __restrict__ cp0,
                                          const float* __restrict__ cq,
                                          u16* __restrict__ state) {
    const int tid = threadIdx.x;
    const int w = tid >> 6, l = tid & 63;
    const int r = l & 15, kg = l >> 4;
    const int row0 = blockIdx.x * 16;

    const float* xrow = x + (size_t)(row0 + r) * DIN + kg * 8;
    const u16*   wrow = Wb + (size_t)(w * 16 + r) * DIN + kg * 8;

    f32x4 acc = {0.0f, 0.0f, 0.0f, 0.0f};
    for (int k0 = 0; k0 < DIN; k0 += 32) {
        float4 xa = *(const float4*)(xrow + k0);
        float4 xb = *(const float4*)(xrow + k0 + 4);
        union { bf16x8 v; unsigned u[4]; } a;
        asm("v_cvt_pk_bf16_f32 %0, %1, %2" : "=v"(a.u[0]) : "v"(xa.x), "v"(xa.y));
        asm("v_cvt_pk_bf16_f32 %0, %1, %2" : "=v"(a.u[1]) : "v"(xa.z), "v"(xa.w));
        asm("v_cvt_pk_bf16_f32 %0, %1, %2" : "=v"(a.u[2]) : "v"(xb.x), "v"(xb.y));
        asm("v_cvt_pk_bf16_f32 %0, %1, %2" : "=v"(a.u[3]) : "v"(xb.z), "v"(xb.w));
        bf16x8 b = *(const bf16x8*)(wrow + k0);
        acc = __builtin_amdgcn_mfma_f32_16x16x32_bf16(a.v, b, acc, 0, 0, 0);
    }

    // D layout (verified rounds 1-10): col q = w*16+r, row = kg*4+i
    const int q = w * 16 + r;
    const float bi = b_in[q], c0q = cp0[q], c1q = cq[q];
    #pragma unroll
    for (int i = 0; i < 4; ++i) {
        float av = acc[i] + bi;
        float e2 = __builtin_amdgcn_exp2f(av * 2.8853900817779268f);   // 2*log2e
        float th = 1.0f - 2.0f * __builtin_amdgcn_rcpf(e2 + 1.0f);     // tanh
        float sv = __builtin_amdgcn_cosf(th * 0.25f) * c0q + c1q;      // cos(th*pi/2)
        state[(size_t)(row0 + kg * 4 + i) * NQ + q] = f2bf(sv);
    }
}

// ---- kB: out = state @ W_out.T + b_out --------------------------------------
// 4096 blocks x 256 thr. Block owns 16 rows; wave w owns cols [w*256, +256).
// Round-4 phase-B pattern (single live accumulator, verified rounds 4-9) with
// round-1's row-major state/Wob reads.
__global__ __launch_bounds__(256) void kB(const u16* __restrict__ state,
                                          const u16* __restrict__ Wob,
                                          const float* __restrict__ b_out,
                                          float* __restrict__ out) {
    const int tid = threadIdx.x;
    const int w = tid >> 6, l = tid & 63;
    const int r = l & 15, kg = l >> 4;
    const int row0 = blockIdx.x * 16;

    const u16* srow = state + (size_t)(row0 + r) * NQ + kg * 8;
    bf16x8 sa0 = *(const bf16x8*)(srow);        // k = kg*8 + j
    bf16x8 sa1 = *(const bf16x8*)(srow + 32);   // k = 32 + kg*8 + j

    const size_t orow = (size_t)(row0 + kg * 4) * DOUT;

    #pragma unroll 4
    for (int nt = 0; nt < 16; ++nt) {
        const int col = w * 256 + nt * 16 + r;
        const u16* wp = Wob + (size_t)col * NQ + kg * 8;
        bf16x8 b0 = *(const bf16x8*)(wp);         // k = kg*8 + j
        bf16x8 b1 = *(const bf16x8*)(wp + 32);    // k = 32 + kg*8 + j
        f32x4 a2 = {0.0f, 0.0f, 0.0f, 0.0f};
        a2 = __builtin_amdgcn_mfma_f32_16x16x32_bf16(sa0, b0, a2, 0, 0, 0);
        a2 = __builtin_amdgcn_mfma_f32_16x16x32_bf16(sa1, b1, a2, 0, 0, 0);
        const float bo = b_out[col];
        #pragma unroll
        for (int i = 0; i < 4; ++i)
            out[orow + (size_t)i * DOUT + col] = a2[i] + bo;
    }
}

extern "C" void kernel_launch(void* const* d_in, const int* in_sizes, int n_in,
                              void* d_out, int out_size, void* d_ws, size_t ws_size,
                              hipStream_t stream) {
    const float* x    = (const float*)d_in[0];
    const float* W_in = (const float*)d_in[1];
    const float* b_in = (const float*)d_in[2];
    const float* qp   = (const float*)d_in[3];
    const float* W_out= (const float*)d_in[4];
    const float* b_out= (const float*)d_in[5];
    float* out = (float*)d_out;

    char* ws = (char*)d_ws;
    u16*   Wb    = (u16*)(ws);               // 128 KB row-major bf16 W_in
    u16*   Wob   = (u16*)(ws + 131072);      // 128 KB row-major bf16 W_out
    float* cp0   = (float*)(ws + 262144);    // 256 B
    float* cq    = (float*)(ws + 262400);    // 256 B
    u16*   state = (u16*)(ws + 1048576);     // 8 MB row-major state

    kP<<<(NQ * DIN + 255) / 256, 256, 0, stream>>>(W_in, W_out, qp, Wb, Wob, cp0, cq);
    kA<<<NB / 16, 256, 0, stream>>>(x, Wb, b_in, cp0, cq, state);
    kB<<<NB / 16, 256, 0, stream>>>(state, Wob, b_out, out);
}

// Round 14
// 167.007 us; speedup vs baseline: 1.5488x; 1.5488x over previous
//
#include <hip/hip_runtime.h>
#include <hip/hip_bf16.h>
#include <math.h>

#define NB 65536
#define DIN 1024
#define NQ 64
#define DOUT 1024

typedef __attribute__((ext_vector_type(8))) short bf16x8;
typedef __attribute__((ext_vector_type(4))) float f32x4;
typedef unsigned short u16;

__device__ __forceinline__ u16 f2bf(float f) {
    union { float f; unsigned u; } v; v.f = f;
    return (u16)((v.u + 0x7fffu + ((v.u >> 16) & 1u)) >> 16);
}

// ---- kP: row-major bf16 weights + per-q constants (round-13 verbatim) -------
__global__ __launch_bounds__(256) void kP(const float* __restrict__ W_in,
                                          const float* __restrict__ W_out,
                                          const float* __restrict__ qp,
                                          u16* __restrict__ Wb,
                                          u16* __restrict__ Wob,
                                          float* __restrict__ cp0,
                                          float* __restrict__ cq) {
    int i = blockIdx.x * 256 + threadIdx.x;
    if (i < NQ * DIN)  Wb[i]  = f2bf(W_in[i]);
    if (i < DOUT * NQ) Wob[i] = f2bf(W_out[i]);
    if (i < NQ) {
        cp0[i] = cosf(qp[i * 3 + 0]);
        cq[i]  = sinf(qp[i * 3 + 1]) * cosf(qp[i * 3 + 2]);
    }
}

// ---- kA: GEMM1 + quantum epilogue, Wb LDS-resident --------------------------
// 512 blocks x 512 thr (8 waves). Block owns 128 rows (wave w: 16); Wb staged
// to LDS ONCE (swizzled: 16B-unit low3 ^= row&7, same formula both sides).
// Weight demand 512->64 MB; x read exactly once. MFMA mappings = R1/R13
// verified; epilogue/state write = R13 verbatim (+ wave row offset).
__global__ __launch_bounds__(512) void kA(const float* __restrict__ x,
                                          const u16* __restrict__ Wb,
                                          const float* __restrict__ b_in,
                                          const float* __restrict__ cp0,
                                          const float* __restrict__ cq,
                                          u16* __restrict__ state) {
    __shared__ u16 WbL[NQ * DIN];                 // 128 KB, [64 rows][128 units]

    const int tid = threadIdx.x;
    const int w = tid >> 6, l = tid & 63;
    const int r = l & 15, kg = l >> 4;
    const int row0 = blockIdx.x * 128 + w * 16;

    // stage Wb: 8192 units of 16B, coalesced; unit low3 XOR row&7
    #pragma unroll
    for (int c = 0; c < 16; ++c) {
        int g   = c * 512 + tid;                  // global unit 0..8191
        int row = g >> 7;                         // 128 units per row
        int u   = g & 127;
        int us  = (u & 120) | ((u ^ row) & 7);
        *(bf16x8*)((char*)WbL + row * 2048 + us * 16) =
            *(const bf16x8*)((const char*)Wb + (size_t)g * 16);
    }
    __syncthreads();

    const float* xrow = x + (size_t)(row0 + r) * DIN + kg * 8;

    f32x4 acc[4] = {f32x4{0,0,0,0}, f32x4{0,0,0,0}, f32x4{0,0,0,0}, f32x4{0,0,0,0}};

    float4 xa = *(const float4*)(xrow);
    float4 xb = *(const float4*)(xrow + 4);
    for (int k0 = 0; k0 < DIN; k0 += 32) {
        float4 na, nb;
        if (k0 < DIN - 32) {                      // 1-deep prefetch
            na = *(const float4*)(xrow + k0 + 32);
            nb = *(const float4*)(xrow + k0 + 36);
        }
        union { bf16x8 v; unsigned u[4]; } a;
        asm("v_cvt_pk_bf16_f32 %0, %1, %2" : "=v"(a.u[0]) : "v"(xa.x), "v"(xa.y));
        asm("v_cvt_pk_bf16_f32 %0, %1, %2" : "=v"(a.u[1]) : "v"(xa.z), "v"(xa.w));
        asm("v_cvt_pk_bf16_f32 %0, %1, %2" : "=v"(a.u[2]) : "v"(xb.x), "v"(xb.y));
        asm("v_cvt_pk_bf16_f32 %0, %1, %2" : "=v"(a.u[3]) : "v"(xb.z), "v"(xb.w));
        #pragma unroll
        for (int n = 0; n < 4; ++n) {
            const int row = n * 16 + r;           // row&7 == r&7
            const int u   = (k0 >> 3) + kg;
            const int us  = (u & 120) | ((u ^ r) & 7);
            bf16x8 b = *(const bf16x8*)((const char*)WbL + row * 2048 + us * 16);
            acc[n] = __builtin_amdgcn_mfma_f32_16x16x32_bf16(a.v, b, acc[n], 0, 0, 0);
        }
        xa = na; xb = nb;
    }

    // D layout: col q = n*16+r, row = kg*4+i (verified R1-R13)
    #pragma unroll
    for (int n = 0; n < 4; ++n) {
        const int q = n * 16 + r;
        const float bi = b_in[q], c0q = cp0[q], c1q = cq[q];
        #pragma unroll
        for (int i = 0; i < 4; ++i) {
            float av = acc[n][i] + bi;
            float e2 = __builtin_amdgcn_exp2f(av * 2.8853900817779268f);   // 2*log2e
            float th = 1.0f - 2.0f * __builtin_amdgcn_rcpf(e2 + 1.0f);     // tanh
            float sv = __builtin_amdgcn_cosf(th * 0.25f) * c0q + c1q;      // cos(th*pi/2)
            state[(size_t)(row0 + kg * 4 + i) * NQ + q] = f2bf(sv);
        }
    }
}

// ---- kB: out = state @ W_out.T + b_out, Wob LDS-resident --------------------
// 512 blocks x 512 thr (8 waves x 16 rows = 128 rows). Wob ([1024][64] u16,
// 8 units/row) staged once, unit ^= row&7. Wave covers all 64 col-tiles.
// State read / D / store = R13 verbatim (+ wave row offset).
__global__ __launch_bounds__(512) void kB(const u16* __restrict__ state,
                                          const u16* __restrict__ Wob,
                                          const float* __restrict__ b_out,
                                          float* __restrict__ out) {
    __shared__ u16 WobL[DOUT * NQ];               // 128 KB, [1024 cols][8 units]

    const int tid = threadIdx.x;
    const int w = tid >> 6, l = tid & 63;
    const int r = l & 15, kg = l >> 4;
    const int row0 = blockIdx.x * 128 + w * 16;

    #pragma unroll
    for (int c = 0; c < 16; ++c) {
        int g   = c * 512 + tid;                  // global unit 0..8191
        int row = g >> 3;                         // 8 units per row
        int us  = (g ^ row) & 7;
        *(bf16x8*)((char*)WobL + row * 128 + us * 16) =
            *(const bf16x8*)((const char*)Wob + (size_t)g * 16);
    }
    __syncthreads();

    const u16* srow = state + (size_t)(row0 + r) * NQ + kg * 8;
    bf16x8 sa0 = *(const bf16x8*)(srow);          // k = kg*8 + j
    bf16x8 sa1 = *(const bf16x8*)(srow + 32);     // k = 32 + kg*8 + j

    const size_t orow = (size_t)(row0 + kg * 4) * DOUT;

    #pragma unroll 4
    for (int nt = 0; nt < 64; ++nt) {
        const int col = nt * 16 + r;              // col&7 == r&7
        const int us0 = (kg     ^ r) & 7;
        const int us1 = ((4+kg) ^ r) & 7;
        bf16x8 b0 = *(const bf16x8*)((const char*)WobL + col * 128 + us0 * 16);
        bf16x8 b1 = *(const bf16x8*)((const char*)WobL + col * 128 + us1 * 16);
        f32x4 a2 = {0.0f, 0.0f, 0.0f, 0.0f};
        a2 = __builtin_amdgcn_mfma_f32_16x16x32_bf16(sa0, b0, a2, 0, 0, 0);
        a2 = __builtin_amdgcn_mfma_f32_16x16x32_bf16(sa1, b1, a2, 0, 0, 0);
        const float bo = b_out[col];
        #pragma unroll
        for (int i = 0; i < 4; ++i)
            out[orow + (size_t)i * DOUT + col] = a2[i] + bo;
    }
}

extern "C" void kernel_launch(void* const* d_in, const int* in_sizes, int n_in,
                              void* d_out, int out_size, void* d_ws, size_t ws_size,
                              hipStream_t stream) {
    const float* x    = (const float*)d_in[0];
    const float* W_in = (const float*)d_in[1];
    const float* b_in = (const float*)d_in[2];
    const float* qp   = (const float*)d_in[3];
    const float* W_out= (const float*)d_in[4];
    const float* b_out= (const float*)d_in[5];
    float* out = (float*)d_out;

    char* ws = (char*)d_ws;
    u16*   Wb    = (u16*)(ws);               // 128 KB row-major bf16 W_in
    u16*   Wob   = (u16*)(ws + 131072);      // 128 KB row-major bf16 W_out
    float* cp0   = (float*)(ws + 262144);    // 256 B
    float* cq    = (float*)(ws + 262400);    // 256 B
    u16*   state = (u16*)(ws + 1048576);     // 8 MB row-major state

    kP<<<(NQ * DIN + 255) / 256, 256, 0, stream>>>(W_in, W_out, qp, Wb, Wob, cp0, cq);
    kA<<<NB / 128, 512, 0, stream>>>(x, Wb, b_in, cp0, cq, state);
    kB<<<NB / 128, 512, 0, stream>>>(state, Wob, b_out, out);
}